// Round 20
// baseline (21.764 us; speedup 1.0000x reference)
//
#include <hip/hip_runtime.h>

#define N1 8192
#define N2 8192
#define KNN 32
#define R2_F32 0.009999999776482582f   // f32(0.1*0.1), bit-exact vs np ref (rounds 2..19)

#define GDIM 10
#define NCELLS (GDIM * GDIM * GDIM)
#define CELL_W 0.109375f               // 7/64: exact in f32
#define INV_W  9.142857142857142f
#define CAP 40                         // bucket capacity; P(cell>40) ~ 1e-9
#define HCAP 128                       // per-query hit buffer (E[hits]~34)
#define PRUNE2 0.0105f                 // cell min-dist^2 prune (margin >> gram noise)

// ---- ws layout ----
// 0    : cnt [1000] i32  (written unconditionally by k_build -- no memset)
// 4096 : pts [1000*CAP] float4 (x,y,z,(float)j), index-sorted within cell
#define WS_CNT 0
#define WS_PTS 4096

#define BW  8                  // waves per build block (512 threads)
#define BSL (N2 / BW)          // 1024 points per wave slice
#define CPB 8                  // cells per build block -> 125 blocks

struct F3 { float x, y, z; };

__device__ __forceinline__ F3 ld3(const float* __restrict__ p, int j) {
    F3 r;
    r.x = p[3 * j + 0];
    r.y = p[3 * j + 1];
    r.z = p[3 * j + 2];
    return r;
}

__device__ __forceinline__ int cell_coord(float v) {
    int c = (int)(v * INV_W);
    return c > (GDIM - 1) ? (GDIM - 1) : c;
}

__device__ __forceinline__ int prefix_lt(unsigned long long m) {
    return (int)__builtin_amdgcn_mbcnt_hi(
        (unsigned)(m >> 32),
        __builtin_amdgcn_mbcnt_lo((unsigned)m, 0u));
}

// Atomic-free build, 8 cells per block (halves the p2 re-scan vs CPB=4).
__global__ __launch_bounds__(512) void k_build(const float* __restrict__ p2,
                                               int* __restrict__ cnt,
                                               float4* __restrict__ pts) {
    __shared__ float4 buf[BW][CPB][CAP];   // 40 KB
    __shared__ int    cl[BW][CPB];
    const int w    = (int)(threadIdx.x >> 6);   // 0..7
    const int lane = (int)(threadIdx.x & 63);
    const int base = (int)blockIdx.x * CPB;     // cells [base, base+8)

    int count[CPB] = {0, 0, 0, 0, 0, 0, 0, 0};
    const int jofs = w * BSL;

    auto proc = [&](const F3& p, int jb) {
        const int cid = (cell_coord(p.x) * GDIM + cell_coord(p.y)) * GDIM + cell_coord(p.z);
        const unsigned dt = (unsigned)(cid - base);
#pragma unroll
        for (int t = 0; t < CPB; ++t) {
            const bool match = (dt == (unsigned)t);
            const unsigned long long m = __ballot(match);
            if (m) {
                const int pos = count[t] + prefix_lt(m);
                if (match && pos < CAP)
                    buf[w][t][pos] = make_float4(p.x, p.y, p.z, (float)(jb + lane));
                count[t] += (int)__popcll(m);
            }
        }
    };

    constexpr int NMB = BSL / 256;   // 4 macro-iterations of 4 chunks
    F3 b0 = ld3(p2, jofs + 0 * 64 + lane);
    F3 b1 = ld3(p2, jofs + 1 * 64 + lane);
    F3 b2 = ld3(p2, jofs + 2 * 64 + lane);
    F3 b3 = ld3(p2, jofs + 3 * 64 + lane);
    for (int mb = 0; mb < NMB; ++mb) {
        const int nb = (mb + 1 < NMB) ? (mb + 1) : 0;
        F3 n0 = ld3(p2, jofs + nb * 256 + 0 * 64 + lane);
        F3 n1 = ld3(p2, jofs + nb * 256 + 1 * 64 + lane);
        F3 n2 = ld3(p2, jofs + nb * 256 + 2 * 64 + lane);
        F3 n3 = ld3(p2, jofs + nb * 256 + 3 * 64 + lane);
        const int jb = jofs + mb * 256;
        proc(b0, jb + 0 * 64);
        proc(b1, jb + 1 * 64);
        proc(b2, jb + 2 * 64);
        proc(b3, jb + 3 * 64);
        b0 = n0; b1 = n1; b2 = n2; b3 = n3;
    }

    if (lane == 0) {
#pragma unroll
        for (int t = 0; t < CPB; ++t) cl[w][t] = count[t];
    }
    __syncthreads();

    // Merge per target cell: wave-order prefix = index order (slices ascend).
#pragma unroll
    for (int t = 0; t < CPB; ++t) {
        int startv = 0, tot = 0;
#pragma unroll
        for (int u = 0; u < BW; ++u) {
            const int cu = cl[u][t];
            if (u < w) startv += cu;
            tot += cu;
        }
        const int st = startv < CAP ? startv : CAP;
        int ns = CAP - st;
        if (count[t] < ns) ns = count[t];
        if (lane < ns) pts[(base + t) * CAP + st + lane] = buf[w][t][lane];
        if (w == 0 && lane == 0) cnt[base + t] = tot;
    }
}

__global__ __launch_bounds__(256) void k_query(
    const float* __restrict__ p1, const float4* __restrict__ pts,
    const int* __restrict__ cnt,
    float* __restrict__ map_f, float* __restrict__ cnt_f, float* __restrict__ out_f)
{
    __shared__ float4 hits[4][HCAP];    // 8 KB, per-wave private
    const int w    = (int)(threadIdx.x >> 6);
    const int lane = (int)(threadIdx.x & 63);
    const int q    = (int)blockIdx.x * 4 + w;

    const float qx = p1[3 * q], qy = p1[3 * q + 1], qz = p1[3 * q + 2];
    // bit-exact numpy-style s1 (do not change)
    const float s1 = __fadd_rn(__fadd_rn(__fmul_rn(qx, qx), __fmul_rn(qy, qy)),
                               __fmul_rn(qz, qz));

    const int cx = cell_coord(qx), cy = cell_coord(qy), cz = cell_coord(qz);

    // Lanes 0..26 own one neighbor cell: length + min-dist^2 prune.
    int len = 0, id = 0;
    if (lane < 27) {
        const int ax = cx + lane / 9 - 1;
        const int ay = cy + (lane / 3) % 3 - 1;
        const int az = cz + lane % 3 - 1;
        const bool valid = (unsigned)ax < GDIM && (unsigned)ay < GDIM && (unsigned)az < GDIM;
        if (valid) {
            id = (ax * GDIM + ay) * GDIM + az;
            const float gx = fmaxf(0.0f, fmaxf((float)ax * CELL_W - qx, qx - (float)(ax + 1) * CELL_W));
            const float gy = fmaxf(0.0f, fmaxf((float)ay * CELL_W - qy, qy - (float)(ay + 1) * CELL_W));
            const float gz = fmaxf(0.0f, fmaxf((float)az * CELL_W - qz, qz - (float)(az + 1) * CELL_W));
            const float mind2 = gx * gx + gy * gy + gz * gz;
            if (mind2 <= PRUNE2) {
                int c = cnt[id];
                len = c < CAP ? c : CAP;
            }
        }
    }

    // Inclusive scan of len over lanes (lanes >= 27 carry T).
    int cum = len;
#pragma unroll
    for (int d = 1; d < 32; d <<= 1) {
        const int v = __shfl_up(cum, d, 64);
        if (lane >= d) cum += v;
    }
    const int T = __shfl(cum, 26, 64);
    const int adj = id * CAP - (cum - len);   // pts_idx = g + adj[run]

    int hcnt = 0;

    // One virtual-concat gather step for candidate g (may be inactive).
    auto gstep = [&](int g) {
        const bool active = g < T;
        int lo = 0;
#pragma unroll
        for (int st = 16; st > 0; st >>= 1) {
            const int v = __shfl(cum, lo + st - 1, 64);
            if (v <= g) lo += st;
        }
        const int aj = __shfl(adj, lo, 64);
        float4 e = make_float4(2.0f, 2.0f, 2.0f, 0.0f);   // dummy: far away
        if (active) e = pts[g + aj];
        // bit-exact f32 gram classification (do not change)
        const float s2  = __fadd_rn(__fadd_rn(__fmul_rn(e.x, e.x), __fmul_rn(e.y, e.y)),
                                    __fmul_rn(e.z, e.z));
        const float dot = __fmaf_rn(qz, e.z, __fmaf_rn(qy, e.y, __fmul_rn(qx, e.x)));
        const float d2  = __fsub_rn(__fadd_rn(s1, s2), __fadd_rn(dot, dot));
        const bool within = active && (d2 <= R2_F32);
        const unsigned long long m = __ballot(within);
        if (m) {
            const int pos = hcnt + prefix_lt(m);
            if (within && pos < HCAP) hits[w][pos] = e;
            hcnt += (int)__popcll(m);
        }
    };

    // Fixed 4-step unrolled gather (covers T <= 256; E[T]~150): the four
    // binsearch+load chains are iteration-independent -> issue concurrently.
    // Only the cheap ballot/hcnt chain is sequential.
    gstep(0 * 64 + lane);
    gstep(1 * 64 + lane);
    gstep(2 * 64 + lane);
    gstep(3 * 64 + lane);
    // Rare tail (T > 256): dynamic loop.
    for (int g0 = 256; g0 < T; g0 += 64) gstep(g0 + lane);

    // Rank-by-counting: output slot = #hits with smaller original index.
    const int cap2 = hcnt < HCAP ? hcnt : HCAP;
    float4 e0, e1;
    int j0 = 0x7FFFFFFF, j1 = 0x7FFFFFFF;
    if (lane < cap2)      { e0 = hits[w][lane];      j0 = (int)e0.w; }
    if (lane + 64 < cap2) { e1 = hits[w][lane + 64]; j1 = (int)e1.w; }
    int r0 = 0, r1 = 0;
#pragma unroll 4
    for (int i = 0; i < cap2; ++i) {
        const int ji = (int)hits[w][i].w;   // wave-uniform address -> broadcast
        r0 += (ji < j0) ? 1 : 0;
        r1 += (ji < j1) ? 1 : 0;
    }

    const int outc = hcnt < KNN ? hcnt : KNN;
    if (lane < cap2 && r0 < KNN) {
        const int s = q * KNN + r0;
        map_f[s] = e0.w;
        float* o = out_f + s * 3;
        o[0] = e0.x; o[1] = e0.y; o[2] = e0.z;
    }
    if (lane + 64 < cap2 && r1 < KNN) {
        const int s = q * KNN + r1;
        map_f[s] = e1.w;
        float* o = out_f + s * 3;
        o[0] = e1.x; o[1] = e1.y; o[2] = e1.z;
    }
    // Zero-fill padded tail (d_out is poisoned; every element must be written).
    if (lane < KNN && lane >= outc) {
        const int s = q * KNN + lane;
        map_f[s] = 0.0f;
        float* o = out_f + s * 3;
        o[0] = 0.0f; o[1] = 0.0f; o[2] = 0.0f;
    }
    if (lane == 0) cnt_f[q] = (float)outc;
}

extern "C" void kernel_launch(void* const* d_in, const int* in_sizes, int n_in,
                              void* d_out, int out_size, void* d_ws, size_t ws_size,
                              hipStream_t stream) {
    const float* p1 = (const float*)d_in[0];
    const float* p2 = (const float*)d_in[1];
    float* out = (float*)d_out;

    float* map_f = out;                        // N1*KNN
    float* cnt_f = out + (size_t)N1 * KNN;     // N1
    float* out_f = cnt_f + N1;                 // N1*KNN*3

    char* ws = (char*)d_ws;
    int*    cnt = (int*)(ws + WS_CNT);
    float4* pts = (float4*)(ws + WS_PTS);

    hipLaunchKernelGGL(k_build, dim3(NCELLS / CPB), dim3(512), 0, stream, p2, cnt, pts);
    hipLaunchKernelGGL(k_query, dim3(N1 / 4),       dim3(256), 0, stream,
                       p1, pts, cnt, map_f, cnt_f, out_f);
}

// Round 21
// 19.477 us; speedup vs baseline: 1.1175x; 1.1175x over previous
//
#include <hip/hip_runtime.h>

#define N1 8192
#define N2 8192
#define KNN 32
#define R2_F32 0.009999999776482582f   // f32(0.1*0.1), bit-exact vs np ref (rounds 2..20)

#define GDIM 10
#define NCELLS (GDIM * GDIM * GDIM)
#define CELL_W 0.109375f               // 7/64: exact in f32
#define INV_W  9.142857142857142f
#define CAP 40                         // bucket capacity; P(cell>40) ~ 1e-9
#define HCAP 128                       // per-query hit buffer (E[hits]~34)
#define PRUNE2 0.0105f                 // cell min-dist^2 prune (margin >> gram noise)

// ---- ws layout ----
// 0    : cnt [1000] i32  (written unconditionally by k_build -- no memset)
// 4096 : pts [1000*CAP] float4 (x,y,z,(float)j), index-sorted within cell
#define WS_CNT 0
#define WS_PTS 4096

#define BW  8                  // waves per build block (512 threads)
#define BSL (N2 / BW)          // 1024 points per wave slice
#define CPB 4                  // cells per build block -> 250 blocks (R19 winner)

struct F3 { float x, y, z; };

__device__ __forceinline__ F3 ld3(const float* __restrict__ p, int j) {
    F3 r;
    r.x = p[3 * j + 0];
    r.y = p[3 * j + 1];
    r.z = p[3 * j + 2];
    return r;
}

__device__ __forceinline__ int cell_coord(float v) {
    int c = (int)(v * INV_W);
    return c > (GDIM - 1) ? (GDIM - 1) : c;
}

__device__ __forceinline__ int prefix_lt(unsigned long long m) {
    return (int)__builtin_amdgcn_mbcnt_hi(
        (unsigned)(m >> 32),
        __builtin_amdgcn_mbcnt_lo((unsigned)m, 0u));
}

// Atomic-free build, 4 cells per block (round-19 winner, verbatim).
__global__ __launch_bounds__(512) void k_build(const float* __restrict__ p2,
                                               int* __restrict__ cnt,
                                               float4* __restrict__ pts) {
    __shared__ float4 buf[BW][CPB][CAP];   // 20 KB
    __shared__ int    cl[BW][CPB];
    const int w    = (int)(threadIdx.x >> 6);   // 0..7
    const int lane = (int)(threadIdx.x & 63);
    const int base = (int)blockIdx.x * CPB;     // cells [base, base+4)

    int count[CPB] = {0, 0, 0, 0};
    const int jofs = w * BSL;

    auto proc = [&](const F3& p, int jb) {
        const int cid = (cell_coord(p.x) * GDIM + cell_coord(p.y)) * GDIM + cell_coord(p.z);
        const unsigned dt = (unsigned)(cid - base);
#pragma unroll
        for (int t = 0; t < CPB; ++t) {
            const bool match = (dt == (unsigned)t);
            const unsigned long long m = __ballot(match);
            if (m) {
                const int pos = count[t] + prefix_lt(m);
                if (match && pos < CAP)
                    buf[w][t][pos] = make_float4(p.x, p.y, p.z, (float)(jb + lane));
                count[t] += (int)__popcll(m);
            }
        }
    };

    constexpr int NMB = BSL / 256;   // 4 macro-iterations of 4 chunks
    F3 b0 = ld3(p2, jofs + 0 * 64 + lane);
    F3 b1 = ld3(p2, jofs + 1 * 64 + lane);
    F3 b2 = ld3(p2, jofs + 2 * 64 + lane);
    F3 b3 = ld3(p2, jofs + 3 * 64 + lane);
    for (int mb = 0; mb < NMB; ++mb) {
        const int nb = (mb + 1 < NMB) ? (mb + 1) : 0;
        F3 n0 = ld3(p2, jofs + nb * 256 + 0 * 64 + lane);
        F3 n1 = ld3(p2, jofs + nb * 256 + 1 * 64 + lane);
        F3 n2 = ld3(p2, jofs + nb * 256 + 2 * 64 + lane);
        F3 n3 = ld3(p2, jofs + nb * 256 + 3 * 64 + lane);
        const int jb = jofs + mb * 256;
        proc(b0, jb + 0 * 64);
        proc(b1, jb + 1 * 64);
        proc(b2, jb + 2 * 64);
        proc(b3, jb + 3 * 64);
        b0 = n0; b1 = n1; b2 = n2; b3 = n3;
    }

    if (lane == 0) {
        cl[w][0] = count[0];
        cl[w][1] = count[1];
        cl[w][2] = count[2];
        cl[w][3] = count[3];
    }
    __syncthreads();

    // Merge per target cell: wave-order prefix = index order (slices ascend).
#pragma unroll
    for (int t = 0; t < CPB; ++t) {
        int startv = 0, tot = 0;
#pragma unroll
        for (int u = 0; u < BW; ++u) {
            const int cu = cl[u][t];
            if (u < w) startv += cu;
            tot += cu;
        }
        const int st = startv < CAP ? startv : CAP;
        int ns = CAP - st;
        if (count[t] < ns) ns = count[t];
        if (lane < ns) pts[(base + t) * CAP + st + lane] = buf[w][t][lane];
        if (w == 0 && lane == 0) cnt[base + t] = tot;
    }
}

__global__ __launch_bounds__(256) void k_query(
    const float* __restrict__ p1, const float4* __restrict__ pts,
    const int* __restrict__ cnt,
    float* __restrict__ map_f, float* __restrict__ cnt_f, float* __restrict__ out_f)
{
    __shared__ float4 hits[4][HCAP];    // 8 KB, per-wave private
    const int w    = (int)(threadIdx.x >> 6);
    const int lane = (int)(threadIdx.x & 63);
    const int q    = (int)blockIdx.x * 4 + w;

    const float qx = p1[3 * q], qy = p1[3 * q + 1], qz = p1[3 * q + 2];
    // bit-exact numpy-style s1 (do not change)
    const float s1 = __fadd_rn(__fadd_rn(__fmul_rn(qx, qx), __fmul_rn(qy, qy)),
                               __fmul_rn(qz, qz));

    const int cx = cell_coord(qx), cy = cell_coord(qy), cz = cell_coord(qz);

    // Lanes 0..26 own one neighbor cell: length + min-dist^2 prune.
    int len = 0, id = 0;
    if (lane < 27) {
        const int ax = cx + lane / 9 - 1;
        const int ay = cy + (lane / 3) % 3 - 1;
        const int az = cz + lane % 3 - 1;
        const bool valid = (unsigned)ax < GDIM && (unsigned)ay < GDIM && (unsigned)az < GDIM;
        if (valid) {
            id = (ax * GDIM + ay) * GDIM + az;
            const float gx = fmaxf(0.0f, fmaxf((float)ax * CELL_W - qx, qx - (float)(ax + 1) * CELL_W));
            const float gy = fmaxf(0.0f, fmaxf((float)ay * CELL_W - qy, qy - (float)(ay + 1) * CELL_W));
            const float gz = fmaxf(0.0f, fmaxf((float)az * CELL_W - qz, qz - (float)(az + 1) * CELL_W));
            const float mind2 = gx * gx + gy * gy + gz * gz;
            if (mind2 <= PRUNE2) {
                int c = cnt[id];
                len = c < CAP ? c : CAP;
            }
        }
    }

    // Inclusive scan of len over lanes (lanes >= 27 carry T).
    int cum = len;
#pragma unroll
    for (int d = 1; d < 32; d <<= 1) {
        const int v = __shfl_up(cum, d, 64);
        if (lane >= d) cum += v;
    }
    const int T = __shfl(cum, 26, 64);
    const int adj = id * CAP - (cum - len);   // pts_idx = g + adj[run]

    int hcnt = 0;

    // One virtual-concat gather step for candidate g (may be inactive per-lane).
    auto gstep = [&](int g) {
        const bool active = g < T;
        int lo = 0;
#pragma unroll
        for (int st = 16; st > 0; st >>= 1) {
            const int v = __shfl(cum, lo + st - 1, 64);
            if (v <= g) lo += st;
        }
        const int aj = __shfl(adj, lo, 64);
        float4 e = make_float4(2.0f, 2.0f, 2.0f, 0.0f);   // dummy: far away
        if (active) e = pts[g + aj];
        // bit-exact f32 gram classification (do not change)
        const float s2  = __fadd_rn(__fadd_rn(__fmul_rn(e.x, e.x), __fmul_rn(e.y, e.y)),
                                    __fmul_rn(e.z, e.z));
        const float dot = __fmaf_rn(qz, e.z, __fmaf_rn(qy, e.y, __fmul_rn(qx, e.x)));
        const float d2  = __fsub_rn(__fadd_rn(s1, s2), __fadd_rn(dot, dot));
        const bool within = active && (d2 <= R2_F32);
        const unsigned long long m = __ballot(within);
        if (m) {
            const int pos = hcnt + prefix_lt(m);
            if (within && pos < HCAP) hits[w][pos] = e;
            hcnt += (int)__popcll(m);
        }
    };

    // Wave-uniform-branch unroll: T is uniform across the wave, so these
    // branches execute EXACTLY the same gsteps as the dynamic loop (no wasted
    // step -- round 20's mistake), but give the scheduler straight-line regions.
    gstep(lane);
    if (T > 64)  gstep(64 + lane);
    if (T > 128) gstep(128 + lane);
    if (T > 192) gstep(192 + lane);
    for (int g0 = 256; g0 < T; g0 += 64) gstep(g0 + lane);   // rare tail

    // Rank-by-counting: output slot = #hits with smaller original index.
    const int cap2 = hcnt < HCAP ? hcnt : HCAP;
    float4 e0, e1;
    int j0 = 0x7FFFFFFF, j1 = 0x7FFFFFFF;
    if (lane < cap2)      { e0 = hits[w][lane];      j0 = (int)e0.w; }
    if (lane + 64 < cap2) { e1 = hits[w][lane + 64]; j1 = (int)e1.w; }
    int r0 = 0, r1 = 0;
#pragma unroll 4
    for (int i = 0; i < cap2; ++i) {
        const int ji = (int)hits[w][i].w;   // wave-uniform address -> broadcast
        r0 += (ji < j0) ? 1 : 0;
        r1 += (ji < j1) ? 1 : 0;
    }

    const int outc = hcnt < KNN ? hcnt : KNN;
    if (lane < cap2 && r0 < KNN) {
        const int s = q * KNN + r0;
        map_f[s] = e0.w;
        float* o = out_f + s * 3;
        o[0] = e0.x; o[1] = e0.y; o[2] = e0.z;
    }
    if (lane + 64 < cap2 && r1 < KNN) {
        const int s = q * KNN + r1;
        map_f[s] = e1.w;
        float* o = out_f + s * 3;
        o[0] = e1.x; o[1] = e1.y; o[2] = e1.z;
    }
    // Zero-fill padded tail (d_out is poisoned; every element must be written).
    if (lane < KNN && lane >= outc) {
        const int s = q * KNN + lane;
        map_f[s] = 0.0f;
        float* o = out_f + s * 3;
        o[0] = 0.0f; o[1] = 0.0f; o[2] = 0.0f;
    }
    if (lane == 0) cnt_f[q] = (float)outc;
}

extern "C" void kernel_launch(void* const* d_in, const int* in_sizes, int n_in,
                              void* d_out, int out_size, void* d_ws, size_t ws_size,
                              hipStream_t stream) {
    const float* p1 = (const float*)d_in[0];
    const float* p2 = (const float*)d_in[1];
    float* out = (float*)d_out;

    float* map_f = out;                        // N1*KNN
    float* cnt_f = out + (size_t)N1 * KNN;     // N1
    float* out_f = cnt_f + N1;                 // N1*KNN*3

    char* ws = (char*)d_ws;
    int*    cnt = (int*)(ws + WS_CNT);
    float4* pts = (float4*)(ws + WS_PTS);

    hipLaunchKernelGGL(k_build, dim3(NCELLS / CPB), dim3(512), 0, stream, p2, cnt, pts);
    hipLaunchKernelGGL(k_query, dim3(N1 / 4),       dim3(256), 0, stream,
                       p1, pts, cnt, map_f, cnt_f, out_f);
}